// Round 1
// baseline (22.271 us; speedup 1.0000x reference)
//
#include <hip/hip_runtime.h>

// PowerDense: y[b,o] = sigmoid( sum_k x[b,k]^kernel[k,o] + bias[o] )
// B=8192, K=128, O=128. x in [0,1).
//
// x^w = exp2(w * log2(x)). log2 computed once per (b,k) and staged in LDS.
// Each block: 8 rows of x; each thread: 4 contiguous outputs.
// w (64 KB) is read from global per-k as float4 (L1/L2 resident, shared by
// all blocks). Transcendental(exp2)-pipe bound by design.

#define B_DIM 8192
#define K_DIM 128
#define O_DIM 128

__global__ __launch_bounds__(256, 4) void powerdense_kernel(
    const float* __restrict__ x,      // [B, K]
    const float* __restrict__ w,      // [K, O]
    const float* __restrict__ bias,   // [O]
    float* __restrict__ out)          // [B, O]
{
    __shared__ float lx[8][K_DIM];    // log2 of the block's 8 x-rows (4 KB)

    const int tid  = threadIdx.x;
    const int r    = tid >> 5;        // 0..7 : row within block
    const int c4   = (tid & 31) * 4;  // 0,4,...,124 : first of 4 output cols
    const int row  = blockIdx.x * 8 + r;

    // ---- stage log2(x) for 8 rows: one float4 per thread, coalesced ----
    const float4 xv = *reinterpret_cast<const float4*>(&x[row * K_DIM + c4]);
    float4 lv;
    lv.x = __builtin_amdgcn_logf(xv.x);   // v_log_f32 (log2)
    lv.y = __builtin_amdgcn_logf(xv.y);
    lv.z = __builtin_amdgcn_logf(xv.z);
    lv.w = __builtin_amdgcn_logf(xv.w);
    *reinterpret_cast<float4*>(&lx[r][c4]) = lv;
    __syncthreads();

    // ---- main contraction: acc[j] += exp2(w[k][c4+j] * lx[r][k]) ----
    float acc0 = 0.f, acc1 = 0.f, acc2 = 0.f, acc3 = 0.f;
    const float4* __restrict__ w4 = reinterpret_cast<const float4*>(w);
    const int wcol = tid & 31;

    #pragma unroll 8
    for (int k = 0; k < K_DIM; ++k) {
        const float  l  = lx[r][k];          // LDS broadcast read
        const float4 wv = w4[k * 32 + wcol]; // 16B global load, L1/L2-hot
        acc0 += __builtin_amdgcn_exp2f(wv.x * l);
        acc1 += __builtin_amdgcn_exp2f(wv.y * l);
        acc2 += __builtin_amdgcn_exp2f(wv.z * l);
        acc3 += __builtin_amdgcn_exp2f(wv.w * l);
    }

    // ---- epilogue: +bias, sigmoid, store ----
    const float4 bv = *reinterpret_cast<const float4*>(&bias[c4]);
    const float LOG2E = 1.4426950408889634f;
    float y0 = acc0 + bv.x, y1 = acc1 + bv.y, y2 = acc2 + bv.z, y3 = acc3 + bv.w;
    float4 s;
    s.x = 1.f / (1.f + __builtin_amdgcn_exp2f(-y0 * LOG2E));
    s.y = 1.f / (1.f + __builtin_amdgcn_exp2f(-y1 * LOG2E));
    s.z = 1.f / (1.f + __builtin_amdgcn_exp2f(-y2 * LOG2E));
    s.w = 1.f / (1.f + __builtin_amdgcn_exp2f(-y3 * LOG2E));
    *reinterpret_cast<float4*>(&out[row * O_DIM + c4]) = s;
}

extern "C" void kernel_launch(void* const* d_in, const int* in_sizes, int n_in,
                              void* d_out, int out_size, void* d_ws, size_t ws_size,
                              hipStream_t stream) {
    const float* x    = (const float*)d_in[0];  // [8192,128]
    const float* w    = (const float*)d_in[1];  // [128,128]
    const float* bias = (const float*)d_in[2];  // [128]
    float* out = (float*)d_out;                 // [8192,128]

    dim3 grid(B_DIM / 8);   // 1024 blocks
    dim3 block(256);
    powerdense_kernel<<<grid, block, 0, stream>>>(x, w, bias, out);
}